// Round 17
// baseline (376.875 us; speedup 1.0000x reference)
//
#include <hip/hip_runtime.h>
#include <math.h>

#define N_NODES 20000
#define SEQ_T   24
#define EMBD    64
#define HL      128     // H_LSTM
#define OUTF    16
#define NEDGE   640000
#define G4      512     // 4*HL
#define KTOT    192     // EMBD + HL
#define ROWS    80      // rows per LSTM block (250 * 80 = 20000 exactly, 1 block/CU)
#define RF      5       // ROWS/16 row-fragments
#define NBLSTM  250
#define LDA     232     // LSTM A-tile leading dim (bf16)
#define WSTRIDE 12288   // per-wave LSTM weight chunk (24 KB)

// CSR build: kernel-boundary sync, zero global atomics
#define NB1     64              // count/fill partition (shrinks gcnt/gdeg 4x)
#define EPB1    (NEDGE/NB1)     // 10000 edges/block
#define NBSC    250             // scan partition over nodes
#define NPB     (N_NODES/NBSC)  // 80 nodes/block
#define CSRT    1024

// conv GEMM tiling
#define CROWS   64
#define CRF     4
#define NCBLK   313     // ceil(20000/64)
#define CPAD    136

typedef __bf16 bf16x8 __attribute__((ext_vector_type(8)));
typedef __bf16 bf16x2 __attribute__((ext_vector_type(2)));
typedef float  f32x4  __attribute__((ext_vector_type(4)));
typedef unsigned short u16;

__device__ __forceinline__ float4 ld4(const float* p){ return *reinterpret_cast<const float4*>(p); }

#define LOG2E 1.44269504f

// ---------------- fused prep: embb + WTp + conv packs + bias ----------------
#define S_EMB   320016                  // (20001*64)/4 threads, 4 elems each
#define S_WTP   (S_EMB + KTOT*G4)       // + 98304
#define S_C1    (S_WTP + 16384)
#define S_C2    (S_C1 + 16384)
#define S_BIAS  (S_C2 + G4)
#define PREPBLK ((S_BIAS + 255)/256)

__global__ __launch_bounds__(256) void prep_all(
    const float* __restrict__ emb,  __bf16* __restrict__ embb,
    const float* __restrict__ Wih,  const float* __restrict__ Whh,
    __bf16* __restrict__ WTp,
    const float* __restrict__ c1W,  __bf16* __restrict__ wc1b,
    const float* __restrict__ c2W,  __bf16* __restrict__ wc2b,
    const float* __restrict__ bi,   const float* __restrict__ bh,
    float* __restrict__ bs)
{
    int gid = blockIdx.x*256 + threadIdx.x;
    if (gid < S_EMB) {
        int i4 = gid*4;
        float4 v = ld4(emb + i4);
        embb[i4+0] = (__bf16)v.x;
        embb[i4+1] = (__bf16)v.y;
        embb[i4+2] = (__bf16)v.z;
        embb[i4+3] = (__bf16)v.w;
    } else if (gid < S_WTP) {
        int idx = gid - S_EMB;
        int ko = idx & 31;
        int c  = (idx >> 5) & 15;
        int gt = (idx >> 9) & 3;
        int kc = (idx >> 11) % 6;
        int w  = idx / WSTRIDE;
        int g  = gt*HL + w*16 + c;
        int kk = kc*32 + ko;
        float v = (kk < EMBD) ? Wih[g*EMBD + kk] : Whh[g*HL + (kk - EMBD)];
        WTp[idx] = (__bf16)v;
    } else if (gid < S_C2) {
        bool c2 = (gid >= S_C1);
        int idx = gid - (c2 ? S_C1 : S_WTP);
        const float* W = c2 ? c2W : c1W;
        __bf16* dst = c2 ? wc2b : wc1b;
        int ko = idx & 31;
        int c  = (idx >> 5) & 15;
        int kc = (idx >> 9) & 3;
        int w  = idx >> 11;
        int g  = w*16 + c;
        int k  = kc*32 + ko;
        dst[idx] = (__bf16)W[k*HL + g];
    } else if (gid < S_BIAS) {
        int i = gid - S_C2;
        bs[i] = bi[i] + bh[i];
    }
}

// ---------------- K1: per-block LDS histogram + LDS deg (64 blocks) ----------------
__global__ __launch_bounds__(CSRT) void csr_count(
    const int* __restrict__ esrc, const int* __restrict__ edst,
    const float* __restrict__ ew,
    u16* __restrict__ rank, u16* __restrict__ gcnt, float* __restrict__ gdeg)
{
    __shared__ int   hist[N_NODES];   // 80000 B
    __shared__ float fdeg[N_NODES];   // 80000 B
    const int tid = threadIdx.x, bid = blockIdx.x;
    const int e0 = bid * EPB1;

    uint4* h4 = reinterpret_cast<uint4*>(hist);
    uint4* f4 = reinterpret_cast<uint4*>(fdeg);
    for (int i = tid; i < N_NODES/4; i += CSRT) {
        h4[i] = make_uint4(0,0,0,0);
        f4[i] = make_uint4(0,0,0,0);
    }
    __syncthreads();

    for (int i = tid; i < EPB1; i += CSRT) {
        int e = e0 + i;
        int d = edst[e];
        rank[e] = (u16)atomicAdd(&hist[d], 1);   // LDS atomic
        atomicAdd(&fdeg[d], ew[e]);              // LDS atomic
    }
    __syncthreads();

    for (int i = tid; i < N_NODES; i += CSRT) {
        gcnt[(size_t)bid*N_NODES + i] = (u16)hist[i];
        gdeg[(size_t)bid*N_NODES + i] = fdeg[i];
    }
}

// ---------------- K2a: per-node exclusive scan over 64 blocks; deg sum -> dinv ----------------
__global__ __launch_bounds__(CSRT) void csr_scan(
    u16* __restrict__ gcnt, const float* __restrict__ gdeg,
    float* __restrict__ dinv, int* __restrict__ tot)
{
    __shared__ u16   ctile[NB1*NPB];   // 10240 B
    __shared__ float dtile[NB1*NPB];   // 20480 B
    const int tid = threadIdx.x, bid = blockIdx.x;
    const int nodes0 = bid * NPB;

    for (int idx = tid; idx < NB1*NPB; idx += CSRT) {
        int b = idx / NPB, i = idx - b*NPB;
        ctile[idx] = gcnt[(size_t)b*N_NODES + nodes0 + i];
        dtile[idx] = gdeg[(size_t)b*N_NODES + nodes0 + i];
    }
    __syncthreads();
    if (tid < NPB) {
        int run = 0; float dsum = 0.f;
        #pragma unroll 4
        for (int b = 0; b < NB1; ++b) {
            int v = ctile[b*NPB + tid];
            ctile[b*NPB + tid] = (u16)run;
            run += v;
            dsum += dtile[b*NPB + tid];
        }
        tot[nodes0 + tid]  = run;
        dinv[nodes0 + tid] = rsqrtf(dsum + 1.0f);
    }
    __syncthreads();
    for (int idx = tid; idx < NB1*NPB; idx += CSRT) {
        int b = idx / NPB, i = idx - b*NPB;
        gcnt[(size_t)b*N_NODES + nodes0 + i] = ctile[idx];
    }
}

// ---------------- K2b: row_start from per-node totals (single block) ----------------
__global__ __launch_bounds__(256) void csr_rowstart(const int* __restrict__ tot,
                                                    int* __restrict__ row_start)
{
    __shared__ int part[NBSC];
    const int t = threadIdx.x;
    if (t < NBSC) {
        int s = 0;
        for (int i = 0; i < NPB; ++i) s += tot[t*NPB + i];
        part[t] = s;
    }
    __syncthreads();
    if (t == 0) {
        int run = 0;
        for (int b = 0; b < NBSC; ++b) { int v = part[b]; part[b] = run; run += v; }
    }
    __syncthreads();
    if (t < NBSC) {
        int base = part[t];
        for (int i = 0; i < NPB; ++i) {
            row_start[t*NPB + i] = base;
            base += tot[t*NPB + i];
        }
        if (t == NBSC - 1) row_start[N_NODES] = base;
    }
}

// ---------------- K3: fill sorted src + norm (atomic-free, 64 blocks) ----------------
__global__ __launch_bounds__(CSRT) void csr_fill(
    const int* __restrict__ esrc, const int* __restrict__ edst,
    const float* __restrict__ ew,
    const u16* __restrict__ rank, const u16* __restrict__ gcnt,
    const int* __restrict__ row_start, const float* __restrict__ dinv,
    int* __restrict__ src_s, float* __restrict__ norm_s)
{
    const int tid = threadIdx.x, bid = blockIdx.x;
    const int e0 = bid * EPB1;
    for (int i = tid; i < EPB1; i += CSRT) {
        int e = e0 + i;
        int d = edst[e], s = esrc[e];
        int pos = row_start[d] + (int)gcnt[(size_t)bid*N_NODES + d] + (int)rank[e];
        src_s[pos]  = s;
        norm_s[pos] = dinv[s] * ew[e] * dinv[d];
    }
}

// ---------------- fused LSTM + conv1 GEMM tail (r16 measured-best, frozen) ----------------
__global__ __launch_bounds__(512, 2) void lstm_fused(
    const int* __restrict__ tokens, const int* __restrict__ lengths,
    const __bf16* __restrict__ embb, const __bf16* __restrict__ WTp,
    const float* __restrict__ bsum, const __bf16* __restrict__ wc1b,
    __bf16* __restrict__ ybf)
{
    __shared__ __align__(16) __bf16 a_lds[ROWS][LDA];
    __shared__ __align__(16) __bf16 hl_lds[ROWS][CPAD];
    __shared__ int tok_lds[ROWS*SEQ_T];
    __shared__ int len_lds[ROWS];

    const int tid = threadIdx.x;
    const int n0  = blockIdx.x * ROWS;
    const int w   = tid >> 6;       // 0..7
    const int l   = tid & 63;
    const int l15 = l & 15, l4 = l >> 4;

    #pragma unroll
    for (int i = 0; i < 4; ++i) {
        int idx = tid + 512*i;
        if (idx < ROWS*SEQ_T) tok_lds[idx] = tokens[n0*SEQ_T + idx];
    }
    if (tid < ROWS) len_lds[tid] = lengths[n0 + tid];

    #pragma unroll
    for (int i = 0; i < 3; ++i) {
        int idx = tid + 512*i;
        if (idx < ROWS*16) {
            int row = idx >> 4, s = idx & 15;
            *reinterpret_cast<uint4*>(&a_lds[row][EMBD + s*8]) = make_uint4(0,0,0,0);
        }
    }

    float bias_v[4];
    #pragma unroll
    for (int gt = 0; gt < 4; ++gt)
        bias_v[gt] = bsum[gt*HL + w*16 + l15];

    bf16x8 wreg[6][4];
    {
        const __bf16* wbase = WTp + (size_t)w * WSTRIDE;
        #pragma unroll
        for (int kc = 0; kc < 6; ++kc)
            #pragma unroll
            for (int gt = 0; gt < 4; ++gt)
                wreg[kc][gt] = *reinterpret_cast<const bf16x8*>(
                    &wbase[(size_t)(((kc*4 + gt)*16 + l15)*32) + l4*8]);
    }

    f32x4 acc[RF][4];
    float c_reg[RF][4];
    {
        f32x4 zz = {0.f,0.f,0.f,0.f};
        #pragma unroll
        for (int rf = 0; rf < RF; ++rf) {
            #pragma unroll
            for (int gt = 0; gt < 4; ++gt) acc[rf][gt] = zz;
            #pragma unroll
            for (int r = 0; r < 4; ++r) c_reg[rf][r] = 0.f;
        }
    }

    for (int t = 0; t < SEQ_T; ++t) {
        #pragma unroll
        for (int i = 0; i < 2; ++i) {
            int idx = tid + 512*i;
            if (idx < ROWS*8) {
                int row = idx >> 3, sl = idx & 7;
                int tok = tok_lds[row*SEQ_T + t];
                *reinterpret_cast<uint4*>(&a_lds[row][sl*8]) =
                    *reinterpret_cast<const uint4*>(&embb[(size_t)tok*EMBD + sl*8]);
            }
        }
        __syncthreads();

        #pragma unroll
        for (int kc = 0; kc < 6; ++kc)
            #pragma unroll
            for (int rf = 0; rf < RF; ++rf) {
                bf16x8 af = *reinterpret_cast<const bf16x8*>(
                    &a_lds[rf*16 + l15][kc*32 + l4*8]);
                #pragma unroll
                for (int gt = 0; gt < 4; ++gt)
                    acc[rf][gt] = __builtin_amdgcn_mfma_f32_16x16x32_bf16(
                        af, wreg[kc][gt], acc[rf][gt], 0, 0, 0);
            }
        __syncthreads();

        // 8-trans epilogue
        #pragma unroll
        for (int rf = 0; rf < RF; ++rf) {
            f32x4 zi4 = acc[rf][0], zf4 = acc[rf][1];
            f32x4 zg4 = acc[rf][2], zo4 = acc[rf][3];
            #pragma unroll
            for (int r = 0; r < 4; ++r) {
                int row = rf*16 + l4*4 + r;
                float zi = zi4[r] + bias_v[0];
                float zf = zf4[r] + bias_v[1];
                float zg = zg4[r] + bias_v[2];
                float zo = zo4[r] + bias_v[3];
                float ef = __builtin_amdgcn_exp2f(-LOG2E*zf);
                float ei = __builtin_amdgcn_exp2f(-LOG2E*zi);
                float eg = __builtin_amdgcn_exp2f(2.0f*LOG2E*zg);
                float sf  = __builtin_amdgcn_rcpf(1.0f + ef);
                float rig = __builtin_amdgcn_rcpf((1.0f + ei)*(eg + 1.0f));
                float cc = sf*c_reg[rf][r] + (eg - 1.0f)*rig;
                c_reg[rf][r] = cc;
                float eo = __builtin_amdgcn_exp2f(-LOG2E*zo);
                float ec = __builtin_amdgcn_exp2f(2.0f*LOG2E*cc);
                float rh = __builtin_amdgcn_rcpf((1.0f + eo)*(ec + 1.0f));
                float h = (ec - 1.0f)*rh;
                int j = w*16 + l15;
                a_lds[row][EMBD + j] = (__bf16)h;
                if (len_lds[row] == t + 1)
                    hl_lds[row][j] = (__bf16)h;
            }
            f32x4 zz = {0.f,0.f,0.f,0.f};
            acc[rf][0] = zz; acc[rf][1] = zz; acc[rf][2] = zz; acc[rf][3] = zz;
        }
    }

    __syncthreads();   // publish hl_lds

    // conv1 GEMM tail
    {
        bf16x8 wb1[4];
        #pragma unroll
        for (int kc = 0; kc < 4; ++kc)
            wb1[kc] = *reinterpret_cast<const bf16x8*>(
                &wc1b[(size_t)(((w*4 + kc)*16 + l15)*32) + l4*8]);
        int j = w*16 + l15;
        #pragma unroll
        for (int rf = 0; rf < RF; ++rf) {
            f32x4 a2 = {0.f,0.f,0.f,0.f};
            #pragma unroll
            for (int kc = 0; kc < 4; ++kc) {
                bf16x8 af = *reinterpret_cast<const bf16x8*>(
                    &hl_lds[rf*16 + l15][kc*32 + l4*8]);
                a2 = __builtin_amdgcn_mfma_f32_16x16x32_bf16(af, wb1[kc], a2, 0, 0, 0);
            }
            #pragma unroll
            for (int r = 0; r < 4; ++r)
                ybf[(size_t)(n0 + rf*16 + l4*4 + r)*HL + j] = (__bf16)a2[r];
        }
    }
}

// ---------------- gather1 + conv2 GEMM fused ----------------
// 313 blocks x 256 thr; wave wv gathers nodes wv+4r (r=0..15) into LDS bf16 tile,
// then conv2 GEMM in-block -> y2 (x2b). Reads ybf, writes x2b: no aliasing.
__global__ __launch_bounds__(256) void gcn_gather_gemm(
    const int* __restrict__ row_start, const int* __restrict__ src_s,
    const float* __restrict__ norm_s, const float* __restrict__ dinv,
    const __bf16* __restrict__ y, const float* __restrict__ b,
    const __bf16* __restrict__ wc2b, __bf16* __restrict__ y2, int N)
{
    __shared__ __align__(16) __bf16 a_lds[CROWS][CPAD];
    const int tid = threadIdx.x;
    const int n0 = blockIdx.x * CROWS;
    const int wv = tid >> 6, ln = tid & 63;
    const int l15 = ln & 15, l4 = ln >> 4;

    // Phase A: gather + bias + relu for 64 nodes
    for (int r = 0; r < 16; ++r) {
        int row = wv + 4*r;
        int n = n0 + row;
        float ax = 0.f, ay = 0.f;
        if (n < N) {
            const int beg = row_start[n], end = row_start[n+1];
            int p = beg;
            for (; p + 4 <= end; p += 4) {
                int   s0 = src_s[p+0], s1 = src_s[p+1], s2 = src_s[p+2], s3 = src_s[p+3];
                float w0 = norm_s[p+0], w1 = norm_s[p+1], w2 = norm_s[p+2], w3 = norm_s[p+3];
                bf16x2 v0 = *reinterpret_cast<const bf16x2*>(y + (size_t)s0*HL + ln*2);
                bf16x2 v1 = *reinterpret_cast<const bf16x2*>(y + (size_t)s1*HL + ln*2);
                bf16x2 v2 = *reinterpret_cast<const bf16x2*>(y + (size_t)s2*HL + ln*2);
                bf16x2 v3 = *reinterpret_cast<const bf16x2*>(y + (size_t)s3*HL + ln*2);
                ax = fmaf(w0, (float)v0[0], ax); ay = fmaf(w0, (float)v0[1], ay);
                ax = fmaf(w1, (float)v1[0], ax); ay = fmaf(w1, (float)v1[1], ay);
                ax = fmaf(w2, (float)v2[0], ax); ay = fmaf(w2, (float)v2[1], ay);
                ax = fmaf(w3, (float)v3[0], ax); ay = fmaf(w3, (float)v3[1], ay);
            }
            for (; p < end; ++p) {
                int s = src_s[p];
                float nrm = norm_s[p];
                bf16x2 v = *reinterpret_cast<const bf16x2*>(y + (size_t)s*HL + ln*2);
                ax = fmaf(nrm, (float)v[0], ax);
                ay = fmaf(nrm, (float)v[1], ay);
            }
            float di = dinv[n];
            float sl = di*di;
            bf16x2 vs = *reinterpret_cast<const bf16x2*>(y + (size_t)n*HL + ln*2);
            ax = fmaf(sl, (float)vs[0], ax);
            ay = fmaf(sl, (float)vs[1], ay);
            float2 bb = *reinterpret_cast<const float2*>(b + ln*2);
            ax = fmaxf(ax + bb.x, 0.f);
            ay = fmaxf(ay + bb.y, 0.f);
        }
        bf16x2 o;
        o[0] = (__bf16)ax; o[1] = (__bf16)ay;
        *reinterpret_cast<bf16x2*>(&a_lds[row][ln*2]) = o;
    }
    __syncthreads();

    // Phase B: conv2 GEMM; wave wv covers col groups cg = wv*2 + q (q=0,1)
    bf16x8 wb[4][2];
    #pragma unroll
    for (int q = 0; q < 2; ++q) {
        int cg = wv*2 + q;
        #pragma unroll
        for (int kc = 0; kc < 4; ++kc)
            wb[kc][q] = *reinterpret_cast<const bf16x8*>(
                &wc2b[(size_t)(((cg*4 + kc)*16 + l15)*32) + l4*8]);
    }
    f32x4 acc[CRF][2];
    {
        f32x4 zz = {0.f,0.f,0.f,0.f};
        #pragma unroll
        for (int rf = 0; rf < CRF; ++rf) { acc[rf][0] = zz; acc[rf][1] = zz; }
    }
    #pragma unroll
    for (int kc = 0; kc < 4; ++kc)
        #pragma unroll
        for (int rf = 0; rf < CRF; ++rf) {
            bf16x8 af = *reinterpret_cast<const bf16x8*>(
                &a_lds[rf*16 + l15][kc*32 + l4*8]);
            acc[rf][0] = __builtin_amdgcn_mfma_f32_16x16x32_bf16(af, wb[kc][0], acc[rf][0], 0, 0, 0);
            acc[rf][1] = __builtin_amdgcn_mfma_f32_16x16x32_bf16(af, wb[kc][1], acc[rf][1], 0, 0, 0);
        }
    #pragma unroll
    for (int rf = 0; rf < CRF; ++rf)
        #pragma unroll
        for (int q = 0; q < 2; ++q) {
            int j = (wv*2 + q)*16 + l15;
            #pragma unroll
            for (int r = 0; r < 4; ++r) {
                int n = n0 + rf*16 + l4*4 + r;
                if (n < N) y2[(size_t)n*HL + j] = (__bf16)acc[rf][q][r];
            }
        }
}

// ---------------- gather2 + fc fused ----------------
__global__ __launch_bounds__(256) void gcn_gather_fc(
    const int* __restrict__ row_start, const int* __restrict__ src_s,
    const float* __restrict__ norm_s, const float* __restrict__ dinv,
    const __bf16* __restrict__ y, const float* __restrict__ b,
    const float* __restrict__ fcW, const float* __restrict__ fcb,
    float* __restrict__ fcout, int N)
{
    __shared__ float xrow[4][HL];
    const int tid = threadIdx.x;
    int gt = blockIdx.x*256 + tid;
    int n = gt >> 6, lane = gt & 63;
    bool act = (n < N);
    float ax = 0.f, ay = 0.f;
    if (act) {
        const int beg = row_start[n], end = row_start[n+1];
        int p = beg;
        for (; p + 4 <= end; p += 4) {
            int   s0 = src_s[p+0], s1 = src_s[p+1], s2 = src_s[p+2], s3 = src_s[p+3];
            float w0 = norm_s[p+0], w1 = norm_s[p+1], w2 = norm_s[p+2], w3 = norm_s[p+3];
            bf16x2 v0 = *reinterpret_cast<const bf16x2*>(y + (size_t)s0*HL + lane*2);
            bf16x2 v1 = *reinterpret_cast<const bf16x2*>(y + (size_t)s1*HL + lane*2);
            bf16x2 v2 = *reinterpret_cast<const bf16x2*>(y + (size_t)s2*HL + lane*2);
            bf16x2 v3 = *reinterpret_cast<const bf16x2*>(y + (size_t)s3*HL + lane*2);
            ax = fmaf(w0, (float)v0[0], ax); ay = fmaf(w0, (float)v0[1], ay);
            ax = fmaf(w1, (float)v1[0], ax); ay = fmaf(w1, (float)v1[1], ay);
            ax = fmaf(w2, (float)v2[0], ax); ay = fmaf(w2, (float)v2[1], ay);
            ax = fmaf(w3, (float)v3[0], ax); ay = fmaf(w3, (float)v3[1], ay);
        }
        for (; p < end; ++p) {
            int s = src_s[p];
            float nrm = norm_s[p];
            bf16x2 v = *reinterpret_cast<const bf16x2*>(y + (size_t)s*HL + lane*2);
            ax = fmaf(nrm, (float)v[0], ax);
            ay = fmaf(nrm, (float)v[1], ay);
        }
        float di = dinv[n];
        float sl = di*di;
        bf16x2 vs = *reinterpret_cast<const bf16x2*>(y + (size_t)n*HL + lane*2);
        ax = fmaf(sl, (float)vs[0], ax);
        ay = fmaf(sl, (float)vs[1], ay);
        float2 bb = *reinterpret_cast<const float2*>(b + lane*2);
        ax = fmaxf(ax + bb.x, 0.f);
        ay = fmaxf(ay + bb.y, 0.f);
    }
    int nq = tid >> 6;
    xrow[nq][lane*2]     = ax;
    xrow[nq][lane*2 + 1] = ay;
    __syncthreads();
    if (tid < 64) {
        int q = tid >> 4, o = tid & 15;
        int nn = blockIdx.x*4 + q;
        if (nn < N) {
            float a = fcb[o];
            #pragma unroll 8
            for (int k = 0; k < HL; ++k)
                a = fmaf(xrow[q][k], fcW[k*OUTF + o], a);
            fcout[(size_t)nn*OUTF + o] = a;
        }
    }
}

extern "C" void kernel_launch(void* const* d_in, const int* in_sizes, int n_in,
                              void* d_out, int out_size, void* d_ws, size_t ws_size,
                              hipStream_t stream)
{
    const int*   x_tokens = (const int*)d_in[0];
    const int*   lengths  = (const int*)d_in[1];
    const int*   eidx     = (const int*)d_in[2];
    const float* ew       = (const float*)d_in[3];
    const float* emb      = (const float*)d_in[4];
    const float* W_ih     = (const float*)d_in[5];
    const float* W_hh     = (const float*)d_in[6];
    const float* b_ih     = (const float*)d_in[7];
    const float* b_hh     = (const float*)d_in[8];
    const float* c1W      = (const float*)d_in[9];
    const float* c1b      = (const float*)d_in[10];
    const float* c2W      = (const float*)d_in[11];
    const float* c2b      = (const float*)d_in[12];
    const float* fcW      = (const float*)d_in[13];
    const float* fcb      = (const float*)d_in[14];
    float* out = (float*)d_out;

    const int* esrc = eidx;
    const int* edst = eidx + NEDGE;

    char* ws = (char*)d_ws;
    size_t off = 0;
    auto take = [&](size_t bytes) -> char* {
        char* p = ws + off;
        off = (off + bytes + 255) & ~(size_t)255;
        return p;
    };
    __bf16* embb = (__bf16*)take((size_t)(N_NODES + 1) * EMBD * sizeof(__bf16));
    __bf16* WTp  = (__bf16*)take((size_t)KTOT * G4 * sizeof(__bf16));
    __bf16* wc1b = (__bf16*)take((size_t)HL * HL * sizeof(__bf16));
    __bf16* wc2b = (__bf16*)take((size_t)HL * HL * sizeof(__bf16));
    float* bsum  = (float*)take((size_t)G4 * sizeof(float));
    __bf16* ybf  = (__bf16*)take((size_t)N_NODES * HL * sizeof(__bf16));
    __bf16* x2b  = (__bf16*)take((size_t)N_NODES * HL * sizeof(__bf16));
    float* dinvb = (float*)take((size_t)N_NODES * sizeof(float));
    u16*   rankb = (u16*)  take((size_t)NEDGE * sizeof(u16));             // 1.25 MB
    u16*   gcnt  = (u16*)  take((size_t)NB1 * N_NODES * sizeof(u16));     // 2.5 MB
    float* gdeg  = (float*)take((size_t)NB1 * N_NODES * sizeof(float));   // 5 MB
    int*   totb  = (int*)  take((size_t)N_NODES * sizeof(int));
    int*   rowst = (int*)  take((size_t)(N_NODES + 1) * sizeof(int));
    int*   srcS  = (int*)  take((size_t)NEDGE * sizeof(int));
    float* nrmS  = (float*)take((size_t)NEDGE * sizeof(float));

    prep_all<<<PREPBLK, 256, 0, stream>>>(emb, embb, W_ih, W_hh, WTp,
                                          c1W, wc1b, c2W, wc2b, b_ih, b_hh, bsum);

    csr_count<<<NB1, CSRT, 0, stream>>>(esrc, edst, ew, rankb, gcnt, gdeg);
    csr_scan<<<NBSC, CSRT, 0, stream>>>(gcnt, gdeg, dinvb, totb);
    csr_rowstart<<<1, 256, 0, stream>>>(totb, rowst);
    csr_fill<<<NB1, CSRT, 0, stream>>>(esrc, edst, ew, rankb, gcnt, rowst,
                                       dinvb, srcS, nrmS);

    lstm_fused<<<NBLSTM, 512, 0, stream>>>(x_tokens, lengths, embb, WTp, bsum,
                                           wc1b, ybf);

    gcn_gather_gemm<<<NCBLK, 256, 0, stream>>>(rowst, srcS, nrmS, dinvb, ybf,
                                               c1b, wc2b, x2b, N_NODES);

    const int gathBlocks = (N_NODES*64 + 255)/256;   // 5000
    gcn_gather_fc<<<gathBlocks, 256, 0, stream>>>(rowst, srcS, nrmS, dinvb, x2b,
                                                  c2b, fcW, fcb, out, N_NODES);
}

// Round 18
// 286.766 us; speedup vs baseline: 1.3142x; 1.3142x over previous
//
#include <hip/hip_runtime.h>
#include <math.h>

#define N_NODES 20000
#define SEQ_T   24
#define EMBD    64
#define HL      128     // H_LSTM
#define OUTF    16
#define NEDGE   640000
#define G4      512     // 4*HL
#define KTOT    192     // EMBD + HL
#define ROWS    80      // rows per LSTM block (250 * 80 = 20000 exactly, 1 block/CU)
#define RF      5       // ROWS/16 row-fragments
#define NBLSTM  250
#define LDA     232     // LSTM A-tile leading dim (bf16)
#define WSTRIDE 12288   // per-wave LSTM weight chunk (24 KB)

// CSR build: 4 kernels, kernel-boundary sync, zero global atomics, zero spin
#define NBCSR   250
#define EPB     (NEDGE/NBCSR)   // 2560 edges/block
#define NPB     (N_NODES/NBCSR) // 80 nodes/block
#define CSRT    1024

// conv GEMM tiling
#define CROWS   64
#define CRF     4
#define NCBLK   313     // ceil(20000/64)
#define CPAD    136

typedef __bf16 bf16x8 __attribute__((ext_vector_type(8)));
typedef __bf16 bf16x2 __attribute__((ext_vector_type(2)));
typedef float  f32x4  __attribute__((ext_vector_type(4)));
typedef unsigned short u16;

__device__ __forceinline__ float4 ld4(const float* p){ return *reinterpret_cast<const float4*>(p); }

#define LOG2E 1.44269504f

// ---------------- fused prep: embb + WTp + conv packs + bias ----------------
#define S_EMB   320016                  // (20001*64)/4 threads, 4 elems each
#define S_WTP   (S_EMB + KTOT*G4)       // + 98304
#define S_C1    (S_WTP + 16384)
#define S_C2    (S_C1 + 16384)
#define S_BIAS  (S_C2 + G4)
#define PREPBLK ((S_BIAS + 255)/256)

__global__ __launch_bounds__(256) void prep_all(
    const float* __restrict__ emb,  __bf16* __restrict__ embb,
    const float* __restrict__ Wih,  const float* __restrict__ Whh,
    __bf16* __restrict__ WTp,
    const float* __restrict__ c1W,  __bf16* __restrict__ wc1b,
    const float* __restrict__ c2W,  __bf16* __restrict__ wc2b,
    const float* __restrict__ bi,   const float* __restrict__ bh,
    float* __restrict__ bs)
{
    int gid = blockIdx.x*256 + threadIdx.x;
    if (gid < S_EMB) {
        int i4 = gid*4;
        float4 v = ld4(emb + i4);
        embb[i4+0] = (__bf16)v.x;
        embb[i4+1] = (__bf16)v.y;
        embb[i4+2] = (__bf16)v.z;
        embb[i4+3] = (__bf16)v.w;
    } else if (gid < S_WTP) {
        int idx = gid - S_EMB;
        int ko = idx & 31;
        int c  = (idx >> 5) & 15;
        int gt = (idx >> 9) & 3;
        int kc = (idx >> 11) % 6;
        int w  = idx / WSTRIDE;
        int g  = gt*HL + w*16 + c;
        int kk = kc*32 + ko;
        float v = (kk < EMBD) ? Wih[g*EMBD + kk] : Whh[g*HL + (kk - EMBD)];
        WTp[idx] = (__bf16)v;
    } else if (gid < S_C2) {
        bool c2 = (gid >= S_C1);
        int idx = gid - (c2 ? S_C1 : S_WTP);
        const float* W = c2 ? c2W : c1W;
        __bf16* dst = c2 ? wc2b : wc1b;
        int ko = idx & 31;
        int c  = (idx >> 5) & 15;
        int kc = (idx >> 9) & 3;
        int w  = idx >> 11;
        int g  = w*16 + c;
        int k  = kc*32 + ko;
        dst[idx] = (__bf16)W[k*HL + g];
    } else if (gid < S_BIAS) {
        int i = gid - S_C2;
        bs[i] = bi[i] + bh[i];
    }
}

// ---------------- K1: per-block LDS histogram + LDS deg; rank + publish rows ----------------
__global__ __launch_bounds__(CSRT) void csr_count(
    const int* __restrict__ esrc, const int* __restrict__ edst,
    const float* __restrict__ ew,
    int* __restrict__ rank, u16* __restrict__ gcnt, float* __restrict__ gdeg)
{
    __shared__ int   hist[N_NODES];   // 80000 B
    __shared__ float fdeg[N_NODES];   // 80000 B
    const int tid = threadIdx.x, bid = blockIdx.x;
    const int e0 = bid * EPB;

    uint4* h4 = reinterpret_cast<uint4*>(hist);
    uint4* f4 = reinterpret_cast<uint4*>(fdeg);
    for (int i = tid; i < N_NODES/4; i += CSRT) {
        h4[i] = make_uint4(0,0,0,0);
        f4[i] = make_uint4(0,0,0,0);
    }
    __syncthreads();

    #pragma unroll
    for (int k = 0; k < 3; ++k) {
        int i = tid + CSRT*k;
        if (k < 2 || i < EPB) {
            int e = e0 + i;
            int d = edst[e];
            rank[e] = atomicAdd(&hist[d], 1);      // LDS atomic (fast)
            atomicAdd(&fdeg[d], ew[e]);            // LDS atomic (fast)
        }
    }
    __syncthreads();

    for (int i = tid; i < N_NODES; i += CSRT) {
        gcnt[(size_t)bid*N_NODES + i] = (u16)hist[i];
        gdeg[(size_t)bid*N_NODES + i] = fdeg[i];
    }
}

// ---------------- K2a: per-node exclusive scan over blocks -> bases; deg sum -> dinv ----------------
__global__ __launch_bounds__(CSRT) void csr_scan(
    u16* __restrict__ gcnt, const float* __restrict__ gdeg,
    float* __restrict__ dinv, int* __restrict__ tot)
{
    __shared__ u16   ctile[NBCSR*NPB];   // 40000 B
    __shared__ float dtile[NBCSR*NPB];   // 80000 B
    const int tid = threadIdx.x, bid = blockIdx.x;
    const int nodes0 = bid * NPB;

    for (int idx = tid; idx < NBCSR*NPB; idx += CSRT) {
        int b = idx / NPB, i = idx - b*NPB;
        ctile[idx] = gcnt[(size_t)b*N_NODES + nodes0 + i];
        dtile[idx] = gdeg[(size_t)b*N_NODES + nodes0 + i];
    }
    __syncthreads();
    if (tid < NPB) {
        int run = 0; float dsum = 0.f;
        for (int b = 0; b < NBCSR; ++b) {
            int v = ctile[b*NPB + tid];
            ctile[b*NPB + tid] = (u16)run;
            run += v;
            dsum += dtile[b*NPB + tid];
        }
        tot[nodes0 + tid]  = run;
        dinv[nodes0 + tid] = rsqrtf(dsum + 1.0f);
    }
    __syncthreads();
    for (int idx = tid; idx < NBCSR*NPB; idx += CSRT) {
        int b = idx / NPB, i = idx - b*NPB;
        gcnt[(size_t)b*N_NODES + nodes0 + i] = ctile[idx];
    }
}

// ---------------- K2b: row_start from per-node totals (single block) ----------------
__global__ __launch_bounds__(256) void csr_rowstart(const int* __restrict__ tot,
                                                    int* __restrict__ row_start)
{
    __shared__ int part[NBCSR];
    const int t = threadIdx.x;
    if (t < NBCSR) {
        int s = 0;
        for (int i = 0; i < NPB; ++i) s += tot[t*NPB + i];
        part[t] = s;
    }
    __syncthreads();
    if (t == 0) {
        int run = 0;
        for (int b = 0; b < NBCSR; ++b) { int v = part[b]; part[b] = run; run += v; }
    }
    __syncthreads();
    if (t < NBCSR) {
        int base = part[t];
        for (int i = 0; i < NPB; ++i) {
            row_start[t*NPB + i] = base;
            base += tot[t*NPB + i];
        }
        if (t == NBCSR - 1) row_start[N_NODES] = base;
    }
}

// ---------------- K3: fill sorted src + norm (atomic-free) ----------------
__global__ __launch_bounds__(CSRT) void csr_fill(
    const int* __restrict__ esrc, const int* __restrict__ edst,
    const float* __restrict__ ew,
    const int* __restrict__ rank, const u16* __restrict__ gcnt,
    const int* __restrict__ row_start, const float* __restrict__ dinv,
    int* __restrict__ src_s, float* __restrict__ norm_s)
{
    const int tid = threadIdx.x, bid = blockIdx.x;
    const int e0 = bid * EPB;
    #pragma unroll
    for (int k = 0; k < 3; ++k) {
        int i = tid + CSRT*k;
        if (k < 2 || i < EPB) {
            int e = e0 + i;
            int d = edst[e], s = esrc[e];
            int pos = row_start[d] + (int)gcnt[(size_t)bid*N_NODES + d] + rank[e];
            src_s[pos]  = s;
            norm_s[pos] = dinv[s] * ew[e] * dinv[d];
        }
    }
}

// ---------------- fused LSTM + conv1 GEMM tail (r16 measured-best, frozen) ----------------
__global__ __launch_bounds__(512, 2) void lstm_fused(
    const int* __restrict__ tokens, const int* __restrict__ lengths,
    const __bf16* __restrict__ embb, const __bf16* __restrict__ WTp,
    const float* __restrict__ bsum, const __bf16* __restrict__ wc1b,
    __bf16* __restrict__ ybf)
{
    __shared__ __align__(16) __bf16 a_lds[ROWS][LDA];
    __shared__ __align__(16) __bf16 hl_lds[ROWS][CPAD];
    __shared__ int tok_lds[ROWS*SEQ_T];
    __shared__ int len_lds[ROWS];

    const int tid = threadIdx.x;
    const int n0  = blockIdx.x * ROWS;
    const int w   = tid >> 6;       // 0..7
    const int l   = tid & 63;
    const int l15 = l & 15, l4 = l >> 4;

    #pragma unroll
    for (int i = 0; i < 4; ++i) {
        int idx = tid + 512*i;
        if (idx < ROWS*SEQ_T) tok_lds[idx] = tokens[n0*SEQ_T + idx];
    }
    if (tid < ROWS) len_lds[tid] = lengths[n0 + tid];

    #pragma unroll
    for (int i = 0; i < 3; ++i) {
        int idx = tid + 512*i;
        if (idx < ROWS*16) {
            int row = idx >> 4, s = idx & 15;
            *reinterpret_cast<uint4*>(&a_lds[row][EMBD + s*8]) = make_uint4(0,0,0,0);
        }
    }

    float bias_v[4];
    #pragma unroll
    for (int gt = 0; gt < 4; ++gt)
        bias_v[gt] = bsum[gt*HL + w*16 + l15];

    bf16x8 wreg[6][4];
    {
        const __bf16* wbase = WTp + (size_t)w * WSTRIDE;
        #pragma unroll
        for (int kc = 0; kc < 6; ++kc)
            #pragma unroll
            for (int gt = 0; gt < 4; ++gt)
                wreg[kc][gt] = *reinterpret_cast<const bf16x8*>(
                    &wbase[(size_t)(((kc*4 + gt)*16 + l15)*32) + l4*8]);
    }

    f32x4 acc[RF][4];
    float c_reg[RF][4];
    {
        f32x4 zz = {0.f,0.f,0.f,0.f};
        #pragma unroll
        for (int rf = 0; rf < RF; ++rf) {
            #pragma unroll
            for (int gt = 0; gt < 4; ++gt) acc[rf][gt] = zz;
            #pragma unroll
            for (int r = 0; r < 4; ++r) c_reg[rf][r] = 0.f;
        }
    }

    for (int t = 0; t < SEQ_T; ++t) {
        #pragma unroll
        for (int i = 0; i < 2; ++i) {
            int idx = tid + 512*i;
            if (idx < ROWS*8) {
                int row = idx >> 3, sl = idx & 7;
                int tok = tok_lds[row*SEQ_T + t];
                *reinterpret_cast<uint4*>(&a_lds[row][sl*8]) =
                    *reinterpret_cast<const uint4*>(&embb[(size_t)tok*EMBD + sl*8]);
            }
        }
        __syncthreads();

        #pragma unroll
        for (int kc = 0; kc < 6; ++kc)
            #pragma unroll
            for (int rf = 0; rf < RF; ++rf) {
                bf16x8 af = *reinterpret_cast<const bf16x8*>(
                    &a_lds[rf*16 + l15][kc*32 + l4*8]);
                #pragma unroll
                for (int gt = 0; gt < 4; ++gt)
                    acc[rf][gt] = __builtin_amdgcn_mfma_f32_16x16x32_bf16(
                        af, wreg[kc][gt], acc[rf][gt], 0, 0, 0);
            }
        __syncthreads();

        // 8-trans epilogue
        #pragma unroll
        for (int rf = 0; rf < RF; ++rf) {
            f32x4 zi4 = acc[rf][0], zf4 = acc[rf][1];
            f32x4 zg4 = acc[rf][2], zo4 = acc[rf][3];
            #pragma unroll
            for (int r = 0; r < 4; ++r) {
                int row = rf*16 + l4*4 + r;
                float zi = zi4[r] + bias_v[0];
                float zf = zf4[r] + bias_v[1];
                float zg = zg4[r] + bias_v[2];
                float zo = zo4[r] + bias_v[3];
                float ef = __builtin_amdgcn_exp2f(-LOG2E*zf);
                float ei = __builtin_amdgcn_exp2f(-LOG2E*zi);
                float eg = __builtin_amdgcn_exp2f(2.0f*LOG2E*zg);
                float sf  = __builtin_amdgcn_rcpf(1.0f + ef);
                float rig = __builtin_amdgcn_rcpf((1.0f + ei)*(eg + 1.0f));
                float cc = sf*c_reg[rf][r] + (eg - 1.0f)*rig;
                c_reg[rf][r] = cc;
                float eo = __builtin_amdgcn_exp2f(-LOG2E*zo);
                float ec = __builtin_amdgcn_exp2f(2.0f*LOG2E*cc);
                float rh = __builtin_amdgcn_rcpf((1.0f + eo)*(ec + 1.0f));
                float h = (ec - 1.0f)*rh;
                int j = w*16 + l15;
                a_lds[row][EMBD + j] = (__bf16)h;
                if (len_lds[row] == t + 1)
                    hl_lds[row][j] = (__bf16)h;
            }
            f32x4 zz = {0.f,0.f,0.f,0.f};
            acc[rf][0] = zz; acc[rf][1] = zz; acc[rf][2] = zz; acc[rf][3] = zz;
        }
    }

    __syncthreads();   // publish hl_lds

    // conv1 GEMM tail: y1 = bf16(hl @ c1W), written straight to ybf
    {
        bf16x8 wb1[4];
        #pragma unroll
        for (int kc = 0; kc < 4; ++kc)
            wb1[kc] = *reinterpret_cast<const bf16x8*>(
                &wc1b[(size_t)(((w*4 + kc)*16 + l15)*32) + l4*8]);
        int j = w*16 + l15;
        #pragma unroll
        for (int rf = 0; rf < RF; ++rf) {
            f32x4 a2 = {0.f,0.f,0.f,0.f};
            #pragma unroll
            for (int kc = 0; kc < 4; ++kc) {
                bf16x8 af = *reinterpret_cast<const bf16x8*>(
                    &hl_lds[rf*16 + l15][kc*32 + l4*8]);
                a2 = __builtin_amdgcn_mfma_f32_16x16x32_bf16(af, wb1[kc], a2, 0, 0, 0);
            }
            #pragma unroll
            for (int r = 0; r < 4; ++r)
                ybf[(size_t)(n0 + rf*16 + l4*4 + r)*HL + j] = (__bf16)a2[r];
        }
    }
}

// ---------------- conv GEMM (conv2 only): y_bf16 = x_bf16 @ Wb ----------------
__global__ __launch_bounds__(512) void gemm_mfma(const __bf16* __restrict__ xb,
                                                 const __bf16* __restrict__ Wb,
                                                 __bf16* __restrict__ y, int N)
{
    __shared__ __align__(16) __bf16 a_lds[CROWS][CPAD];
    const int tid = threadIdx.x;
    const int n0 = blockIdx.x * CROWS;
    const int w = tid >> 6, l = tid & 63;
    const int l15 = l & 15, l4 = l >> 4;

    {
        int row = tid >> 3, sl = tid & 7;   // 16 elems per (row, sl)
        int n = n0 + row;
        uint4 v0 = make_uint4(0,0,0,0), v1 = make_uint4(0,0,0,0);
        if (n < N) {
            v0 = *reinterpret_cast<const uint4*>(xb + (size_t)n*HL + sl*16);
            v1 = *reinterpret_cast<const uint4*>(xb + (size_t)n*HL + sl*16 + 8);
        }
        *reinterpret_cast<uint4*>(&a_lds[row][sl*16])     = v0;
        *reinterpret_cast<uint4*>(&a_lds[row][sl*16 + 8]) = v1;
    }

    bf16x8 wb[4];
    #pragma unroll
    for (int kc = 0; kc < 4; ++kc)
        wb[kc] = *reinterpret_cast<const bf16x8*>(
            &Wb[(size_t)(((w*4 + kc)*16 + l15)*32) + l4*8]);

    f32x4 acc[CRF];
    {
        f32x4 zz = {0.f,0.f,0.f,0.f};
        #pragma unroll
        for (int rf = 0; rf < CRF; ++rf) acc[rf] = zz;
    }
    __syncthreads();

    #pragma unroll
    for (int kc = 0; kc < 4; ++kc)
        #pragma unroll
        for (int rf = 0; rf < CRF; ++rf) {
            bf16x8 af = *reinterpret_cast<const bf16x8*>(
                &a_lds[rf*16 + l15][kc*32 + l4*8]);
            acc[rf] = __builtin_amdgcn_mfma_f32_16x16x32_bf16(af, wb[kc], acc[rf], 0, 0, 0);
        }

    int j = w*16 + l15;
    #pragma unroll
    for (int rf = 0; rf < CRF; ++rf)
        #pragma unroll
        for (int r = 0; r < 4; ++r) {
            int n = n0 + rf*16 + l4*4 + r;
            if (n < N) y[(size_t)n*HL + j] = (__bf16)acc[rf][r];
        }
}

// ---------------- fused GCN aggregation ----------------
// MODE 1: out bf16 (conv1 -> x2b). MODE 2: fused fc epilogue (conv2 -> d_out).
template<int MODE>
__global__ __launch_bounds__(256) void gcn_gather_k(
    const int* __restrict__ row_start, const int* __restrict__ src_s,
    const float* __restrict__ norm_s, const float* __restrict__ dinv,
    const __bf16* __restrict__ y, const float* __restrict__ b,
    __bf16* __restrict__ outb,
    const float* __restrict__ fcW, const float* __restrict__ fcb,
    float* __restrict__ fcout, int N)
{
    __shared__ float xrow[4][HL];
    const int tid = threadIdx.x;
    int gt = blockIdx.x*256 + tid;
    int n = gt >> 6, lane = gt & 63;
    bool act = (n < N);
    float ax = 0.f, ay = 0.f;
    if (act) {
        const int beg = row_start[n], end = row_start[n+1];
        int p = beg;
        for (; p + 4 <= end; p += 4) {
            int   s0 = src_s[p+0], s1 = src_s[p+1], s2 = src_s[p+2], s3 = src_s[p+3];
            float w0 = norm_s[p+0], w1 = norm_s[p+1], w2 = norm_s[p+2], w3 = norm_s[p+3];
            bf16x2 v0 = *reinterpret_cast<const bf16x2*>(y + (size_t)s0*HL + lane*2);
            bf16x2 v1 = *reinterpret_cast<const bf16x2*>(y + (size_t)s1*HL + lane*2);
            bf16x2 v2 = *reinterpret_cast<const bf16x2*>(y + (size_t)s2*HL + lane*2);
            bf16x2 v3 = *reinterpret_cast<const bf16x2*>(y + (size_t)s3*HL + lane*2);
            ax = fmaf(w0, (float)v0[0], ax); ay = fmaf(w0, (float)v0[1], ay);
            ax = fmaf(w1, (float)v1[0], ax); ay = fmaf(w1, (float)v1[1], ay);
            ax = fmaf(w2, (float)v2[0], ax); ay = fmaf(w2, (float)v2[1], ay);
            ax = fmaf(w3, (float)v3[0], ax); ay = fmaf(w3, (float)v3[1], ay);
        }
        for (; p < end; ++p) {
            int s = src_s[p];
            float nrm = norm_s[p];
            bf16x2 v = *reinterpret_cast<const bf16x2*>(y + (size_t)s*HL + lane*2);
            ax = fmaf(nrm, (float)v[0], ax);
            ay = fmaf(nrm, (float)v[1], ay);
        }
        float di = dinv[n];
        float sl = di*di;
        bf16x2 vs = *reinterpret_cast<const bf16x2*>(y + (size_t)n*HL + lane*2);
        ax = fmaf(sl, (float)vs[0], ax);
        ay = fmaf(sl, (float)vs[1], ay);
        float2 bb = *reinterpret_cast<const float2*>(b + lane*2);
        ax = fmaxf(ax + bb.x, 0.f);
        ay = fmaxf(ay + bb.y, 0.f);
    }
    if (MODE == 1) {
        if (act) {
            bf16x2 o;
            o[0] = (__bf16)ax; o[1] = (__bf16)ay;
            *reinterpret_cast<bf16x2*>(outb + (size_t)n*HL + lane*2) = o;
        }
    } else {
        int nq = tid >> 6;
        xrow[nq][lane*2]     = ax;
        xrow[nq][lane*2 + 1] = ay;
        __syncthreads();
        if (tid < 64) {
            int q = tid >> 4, o = tid & 15;
            int nn = blockIdx.x*4 + q;
            if (nn < N) {
                float a = fcb[o];
                #pragma unroll 8
                for (int k = 0; k < HL; ++k)
                    a = fmaf(xrow[q][k], fcW[k*OUTF + o], a);
                fcout[(size_t)nn*OUTF + o] = a;
            }
        }
    }
}

extern "C" void kernel_launch(void* const* d_in, const int* in_sizes, int n_in,
                              void* d_out, int out_size, void* d_ws, size_t ws_size,
                              hipStream_t stream)
{
    const int*   x_tokens = (const int*)d_in[0];
    const int*   lengths  = (const int*)d_in[1];
    const int*   eidx     = (const int*)d_in[2];
    const float* ew       = (const float*)d_in[3];
    const float* emb      = (const float*)d_in[4];
    const float* W_ih     = (const float*)d_in[5];
    const float* W_hh     = (const float*)d_in[6];
    const float* b_ih     = (const float*)d_in[7];
    const float* b_hh     = (const float*)d_in[8];
    const float* c1W      = (const float*)d_in[9];
    const float* c1b      = (const float*)d_in[10];
    const float* c2W      = (const float*)d_in[11];
    const float* c2b      = (const float*)d_in[12];
    const float* fcW      = (const float*)d_in[13];
    const float* fcb      = (const float*)d_in[14];
    float* out = (float*)d_out;

    const int* esrc = eidx;
    const int* edst = eidx + NEDGE;

    char* ws = (char*)d_ws;
    size_t off = 0;
    auto take = [&](size_t bytes) -> char* {
        char* p = ws + off;
        off = (off + bytes + 255) & ~(size_t)255;
        return p;
    };
    __bf16* embb = (__bf16*)take((size_t)(N_NODES + 1) * EMBD * sizeof(__bf16));
    __bf16* WTp  = (__bf16*)take((size_t)KTOT * G4 * sizeof(__bf16));
    __bf16* wc1b = (__bf16*)take((size_t)HL * HL * sizeof(__bf16));
    __bf16* wc2b = (__bf16*)take((size_t)HL * HL * sizeof(__bf16));
    float* bsum  = (float*)take((size_t)G4 * sizeof(float));
    __bf16* ybf  = (__bf16*)take((size_t)N_NODES * HL * sizeof(__bf16));
    __bf16* x2b  = (__bf16*)take((size_t)N_NODES * HL * sizeof(__bf16));
    float* dinvb = (float*)take((size_t)N_NODES * sizeof(float));
    int*   rankb = (int*)  take((size_t)NEDGE * sizeof(int));
    u16*   gcnt  = (u16*)  take((size_t)NBCSR * N_NODES * sizeof(u16));   // 10 MB
    float* gdeg  = (float*)take((size_t)NBCSR * N_NODES * sizeof(float)); // 20 MB
    int*   totb  = (int*)  take((size_t)N_NODES * sizeof(int));
    int*   rowst = (int*)  take((size_t)(N_NODES + 1) * sizeof(int));
    int*   srcS  = (int*)  take((size_t)NEDGE * sizeof(int));
    float* nrmS  = (float*)take((size_t)NEDGE * sizeof(float));

    prep_all<<<PREPBLK, 256, 0, stream>>>(emb, embb, W_ih, W_hh, WTp,
                                          c1W, wc1b, c2W, wc2b, b_ih, b_hh, bsum);

    csr_count<<<NBCSR, CSRT, 0, stream>>>(esrc, edst, ew, rankb, gcnt, gdeg);
    csr_scan<<<NBCSR, CSRT, 0, stream>>>(gcnt, gdeg, dinvb, totb);
    csr_rowstart<<<1, 256, 0, stream>>>(totb, rowst);
    csr_fill<<<NBCSR, CSRT, 0, stream>>>(esrc, edst, ew, rankb, gcnt, rowst,
                                         dinvb, srcS, nrmS);

    lstm_fused<<<NBLSTM, 512, 0, stream>>>(x_tokens, lengths, embb, WTp, bsum,
                                           wc1b, ybf);

    const int gathBlocks = (N_NODES*64 + 255)/256;   // 5000

    gcn_gather_k<1><<<gathBlocks, 256, 0, stream>>>(rowst, srcS, nrmS, dinvb, ybf,
                                                    c1b, x2b, nullptr, nullptr, nullptr, N_NODES);
    gemm_mfma<<<NCBLK, 512, 0, stream>>>(x2b, wc2b, ybf, N_NODES);
    gcn_gather_k<2><<<gathBlocks, 256, 0, stream>>>(rowst, srcS, nrmS, dinvb, ybf,
                                                    c2b, nullptr, fcW, fcb, out, N_NODES);
}